// Round 3
// baseline (1091.970 us; speedup 1.0000x reference)
//
#include <hip/hip_runtime.h>
#include <math.h>

#define BB 64
#define TT 4096
#define CC 64

constexpr int L0v = 2048, U0v = 3069, V0v = 1535, P0v = 2048;
constexpr int L1v = 1024, U1v = 1533, V1v = 767,  P1v = 1024;
constexpr int OUTL = 6144;
constexpr long NTOT = (long)BB * TT * CC;
#define VB 34         // pool outputs per tile
#define NB0 46        // ceil(V0v/VB)
#define NB1 23        // ceil(V1v/VB)
#define NTILE ((NB0 + NB1) * 64)
#define SROWS 50      // staged rows per stream
#define CBSTR 65      // E-buffer stride (odd -> conflict-free column reads)

// ---- transpose x[b][t][c] -> xtr[b][c][t], fused global sum/sumsq ----
__global__ __launch_bounds__(256) void transpose_stats(const float* __restrict__ x,
                                                       float* __restrict__ xtr,
                                                       double* __restrict__ part) {
  __shared__ float tile[64][65];
  __shared__ double sd1[256], sd2[256];
  const int tt = blockIdx.x;
  const int b = blockIdx.y;
  const int t0 = tt * 64;
  const long xbase = (long)b * TT * CC + (long)t0 * CC;
  const int tid = threadIdx.x;
  double a = 0, q = 0;
  {
    int c = tid & 63;
    for (int r = tid >> 6; r < 64; r += 4) {
      float v = x[xbase + r * 64 + c];
      tile[r][c] = v;
      a += v; q += (double)v * (double)v;
    }
  }
  sd1[tid] = a; sd2[tid] = q;
  __syncthreads();
  {
    int tl = tid & 63;
    for (int cc = tid >> 6; cc < 64; cc += 4)
      xtr[((long)(b * 64 + cc)) * TT + t0 + tl] = tile[tl][cc];
  }
  for (int s = 128; s > 0; s >>= 1) {
    if (tid < s) { sd1[tid] += sd1[tid + s]; sd2[tid] += sd2[tid + s]; }
    __syncthreads();
  }
  if (tid == 0) {
    part[(b * 64 + tt) * 2] = sd1[0];
    part[(b * 64 + tt) * 2 + 1] = sd2[0];
  }
}

// ---------------- closed-form index helpers ----------------
__device__ __host__ inline int pad_idx(int p, int brk, int dup, int sub) {
  if (p < brk) { int q = p / 3; int r = p - 3 * q; return 2 * q + (r == 2 ? 1 : 0); }
  if (p < brk + 2) return dup;
  return p - sub;
}

__device__ inline int fmap_code(int k) {
  if (k == 0) return 2048 + 0;
  if (k == 1) return 0;
  if (k < 5462) {
    int m = k - 2;
    int c = m / 12;
    int j = m - 12 * c;
    if (j <= 3)  return 2048 + (1 + 9 * c + j);
    if (j == 4)  return 1 + 3 * c;
    if (j <= 8)  return 2048 + (9 * c + j);
    if (j == 9)  return 2 + 3 * c;
    if (j == 10) return 2048 + (9 + 9 * c);
    return 3 + 3 * c;
  }
  return k - 4096;
}

// ---- merged prep: block 0 = stats_final, 1..64 = weight_norm, 65..88 = codes ----
__global__ __launch_bounds__(256) void prep(const double* __restrict__ part,
                                            double* __restrict__ stats,
                                            const float* __restrict__ v,
                                            const float* __restrict__ g,
                                            float* __restrict__ wt,
                                            int* __restrict__ codes) {
  const int blk = blockIdx.x;
  const int tid = threadIdx.x;
  if (blk == 0) {
    __shared__ double s1[256], s2[256];
    double a = 0, q = 0;
    for (int i = tid; i < 4096; i += 256) { a += part[2 * i]; q += part[2 * i + 1]; }
    s1[tid] = a; s2[tid] = q;
    __syncthreads();
    for (int s = 128; s > 0; s >>= 1) {
      if (tid < s) { s1[tid] += s1[tid + s]; s2[tid] += s2[tid + s]; }
      __syncthreads();
    }
    if (tid == 0) {
      double n = (double)NTOT;
      double mean = s1[0] / n;
      double var = (s2[0] - s1[0] * s1[0] / n) / (n - 1.0);
      stats[0] = mean; stats[1] = sqrt(var);
      stats[2] = 0.8 / mean;
      stats[3] = 0.8 / sqrt(var);
    }
  } else if (blk <= 64) {
    int o = blk - 1;
    __shared__ float red[256];
    __shared__ float scale;
    float vv = (tid < 192) ? v[o * 192 + tid] : 0.f;
    red[tid] = vv * vv;
    __syncthreads();
    for (int s = 128; s > 0; s >>= 1) {
      if (tid < s) red[tid] += red[tid + s];
      __syncthreads();
    }
    if (tid == 0) scale = g[o] / sqrtf(red[0]);
    __syncthreads();
    if (tid < 192) {
      int i = tid / 3, k = tid - 3 * i;
      wt[(k * 64 + i) * 64 + o] = scale * vv;
    }
  } else {
    int k = (blk - 65) * 256 + tid;
    if (k < OUTL) {
      int s = fmap_code(k);
      int type, xi, yi = 0;
      if (s < 2048) {
        if ((s & 1) == 0) { type = 0; xi = 2 * s; }
        else { int p = s >> 1; yi = pad_idx(p, 768, 512, 257); xi = 4 * p + 3; type = 2; }
      } else {
        int p = s - 2048;
        if ((p & 1) == 0) { type = 0; xi = p; }
        else { int q = p >> 1; yi = pad_idx(q, 1536, 1024, 513); xi = 2 * q + 1; type = 1; }
      }
      codes[k] = type | (xi << 2) | (yi << 14);
    }
  }
}

// ---- fused conv (stride2, dil3) + bias + maxpool(3,s2,p1) + elu + gauss + bn-partials ----
// E-restructure: for each output u (u=3a+r), all taps share one phase, so
//   m(3a)   = ivm*E1[2a] + 0.2*E0[2a]
//   m(3a+1) = ivs*E1[2a] + 0.2*E0[2a]
//   m(3a+2) = E0[2a+1]
// where E_s[tau] = sum_k sum_c x_s[tau+k][c] * w[k][c][o] are stride-1 convs
// of the RAW streams.  Inner loop is output-stationary with lane = o:
// weights (12/i4) are coalesced per-lane L2 loads held in VGPRs (ping-pong),
// x comes from LDS as uniform-address ds_read_b128 broadcasts (conflict-free,
// one read per stencil row), zero per-element j-forming.  Combination,
// pool, elu, gauss and bn partial sums happen in the epilogue.
__global__ __launch_bounds__(256, 6) void conv_pool(
    const float* __restrict__ x, const float* __restrict__ wt,
    const float* __restrict__ cbias, const double* __restrict__ stats,
    float* __restrict__ y10, float* __restrict__ y11,
    float* __restrict__ part) {
  const int b = blockIdx.x;
  const int jb = blockIdx.y;
  const bool lev0 = jb < NB0;
  const int v0 = (lev0 ? jb : jb - NB0) * VB;
  const int L = lev0 ? L0v : L1v;
  const int U = lev0 ? U0v : U1v;
  const int V = lev0 ? V0v : V1v;
  const int mult = lev0 ? 2 : 4;
  const int off1 = lev0 ? 1 : 3;
  const int mid = lev0 ? 1024 : 512;
  float* __restrict__ y1 = lev0 ? y10 : y11;

  const int tid = threadIdx.x;
  const int lane = tid & 63;
  const int w = tid >> 6;

  const int a0 = (v0 == 0) ? -1 : (2 * v0 - 1) / 3;

  // S0: stream x[mult*t], S1: stream x[mult*t+off1]; 50 rows x 64 ch fp32 each.
  // Overlay: cbf[72][65] E-buffer + red[512] for bn reduce (20768 B < 25600 B).
  __shared__ __align__(16) float S[2 * SROWS * 64];
  float* S0 = S;
  float* S1 = S + SROWS * 64;
  float* cbf = S;
  float* red = S + 72 * CBSTR;

  const float ivm = (float)stats[2];
  const float ivs = (float)stats[3];
  const long xbase = (long)b * TT * CC;

  // ---- stage the two raw streams (clamped rows) ----
  for (int idx = tid; idx < SROWS * 16; idx += 256) {
    int d = idx >> 4, c4 = (idx & 15) * 4;
    int T = 2 * a0 + d;
    int Tc = min(max(T, 0), L - 1);
    float4 v0r = *(const float4*)&x[xbase + (long)(mult * Tc) * CC + c4];
    float4 v1r = *(const float4*)&x[xbase + (long)(mult * Tc + off1) * CC + c4];
    *(float4*)&S0[d * 64 + c4] = v0r;
    *(float4*)&S1[d * 64 + c4] = v1r;
  }
  __syncthreads();

  // ---- FMA phase: each wave owns 12 E0 rows (d=12w+dd) + 6 E1 rows (e=6w+ee) ----
  float accA[12], accB[6];
#pragma unroll
  for (int i = 0; i < 12; i++) accA[i] = 0.f;
#pragma unroll
  for (int i = 0; i < 6; i++) accB[i] = 0.f;

  const float* wl = wt + lane;
  const float* Sb0 = S0 + (12 * w) * 64;
  const float* Sb1 = S1 + (12 * w) * 64;

#define LOADW(wr, i4)                                        \
  {                                                          \
    _Pragma("unroll")                                        \
    for (int k = 0; k < 3; k++)                              \
      _Pragma("unroll")                                      \
      for (int di = 0; di < 4; di++)                         \
        wr[k * 4 + di] = wl[(k * 64 + (i4) * 4 + di) * 64];  \
  }

#define FMA4(A, xv, wr, kk)                                  \
  {                                                          \
    A = fmaf(xv.x, wr[(kk) * 4 + 0], A);                     \
    A = fmaf(xv.y, wr[(kk) * 4 + 1], A);                     \
    A = fmaf(xv.z, wr[(kk) * 4 + 2], A);                     \
    A = fmaf(xv.w, wr[(kk) * 4 + 3], A);                     \
  }

#define FMABLK(wr, i4)                                                   \
  {                                                                      \
    const float* p0 = Sb0 + (i4) * 4;                                    \
    _Pragma("unroll")                                                    \
    for (int t = 0; t < 14; t++) {                                       \
      float4 xv = *(const float4*)(p0 + t * 64);                         \
      if (t < 12)            FMA4(accA[t], xv, wr, 0);                   \
      if (t >= 1 && t <= 12) FMA4(accA[t - 1], xv, wr, 1);               \
      if (t >= 2)            FMA4(accA[t - 2], xv, wr, 2);               \
    }                                                                    \
    const float* p1 = Sb1 + (i4) * 4;                                    \
    _Pragma("unroll")                                                    \
    for (int t = 0; t < 13; t++) {                                       \
      float4 xv = *(const float4*)(p1 + t * 64);                         \
      if ((t & 1) == 0) {                                                \
        if (t / 2 < 6)  FMA4(accB[t / 2], xv, wr, 0);                    \
        if (t >= 2)     FMA4(accB[t / 2 - 1], xv, wr, 2);                \
      } else {                                                           \
        FMA4(accB[(t - 1) / 2], xv, wr, 1);                              \
      }                                                                  \
    }                                                                    \
  }

  {
    float wa[12], wb[12];
    LOADW(wa, 0);
    for (int i2 = 0; i2 < 8; i2++) {
      LOADW(wb, 2 * i2 + 1);
      FMABLK(wa, 2 * i2);
      if (i2 < 7) LOADW(wa, 2 * i2 + 2);
      FMABLK(wb, 2 * i2 + 1);
    }
  }

  __syncthreads();   // streams dead; write E-buffer overlay
#pragma unroll
  for (int dd = 0; dd < 12; dd++)
    cbf[(12 * w + dd) * CBSTR + lane] = accA[dd];
#pragma unroll
  for (int ee = 0; ee < 6; ee++)
    cbf[(48 + 6 * w + ee) * CBSTR + lane] = accB[ee];
  __syncthreads();

  // ---- combine + pool + elu + gauss + bn partials ----
  const int o = tid >> 2;
  const float bias = cbias[o];
  float a1 = 0.f, a2 = 0.f;
  for (int vq = tid & 3; vq < VB; vq += 4) {
    int v = v0 + vq;
    if (v < V) {
      float m3 = -INFINITY;
#pragma unroll
      for (int p = 0; p < 3; p++) {
        int u = 2 * v - 1 + p;
        float mv = -INFINITY;
        if (u >= 0 && u < U) {
          int a = u / 3;
          int r = u - 3 * a;
          int ai = a - a0;
          if (r == 2) {
            mv = cbf[(2 * ai + 1) * CBSTR + o] + bias;
          } else {
            float e1 = cbf[(48 + ai) * CBSTR + o];
            float e0 = cbf[(2 * ai) * CBSTR + o];
            mv = fmaf(r ? ivs : ivm, e1, fmaf(0.2f, e0, bias));
          }
        }
        m3 = fmaxf(m3, mv);
      }
      float e = (m3 > 0.f) ? m3 : (expf(m3) - 1.f);
      float y = expf(-0.5f * e * e);
      y1[(long)(b * 64 + o) * V + v] = y;
      float wv = (v < mid) ? (float)(2 - (v & 1)) : ((v == mid) ? 2.f : 1.f);
      a1 += wv * y;
      a2 += wv * y * y;
    }
  }
  red[o * 4 + (tid & 3)] = a1;
  red[256 + o * 4 + (tid & 3)] = a2;
  __syncthreads();
  if (tid < 64) {
    float s1 = red[tid * 4] + red[tid * 4 + 1] + red[tid * 4 + 2] + red[tid * 4 + 3];
    float s2 = red[256 + tid * 4] + red[256 + tid * 4 + 1] + red[256 + tid * 4 + 2] + red[256 + tid * 4 + 3];
    long tile = (long)jb * 64 + b;
    part[tile * 128 + tid * 2] = s1;
    part[tile * 128 + tid * 2 + 1] = s2;
  }
#undef LOADW
#undef FMA4
#undef FMABLK
}

// ---- bn reduce over per-tile partials -> affine coefficients z = A*y + B ----
__global__ __launch_bounds__(256) void bn_reduce(const float* __restrict__ part,
                                                 const float* __restrict__ gamma,
                                                 const float* __restrict__ beta,
                                                 float* __restrict__ cf0,
                                                 float* __restrict__ cf1) {
  const int bc = blockIdx.x;          // 0..127
  const int lev = bc >> 6, c = bc & 63;
  const long t_lo = lev ? (long)NB0 * 64 : 0;
  const long t_hi = lev ? (long)(NB0 + NB1) * 64 : (long)NB0 * 64;
  const int tid = threadIdx.x;
  double a = 0, q = 0;
  for (long t = t_lo + tid; t < t_hi; t += 256) {
    a += part[t * 128 + c * 2];
    q += part[t * 128 + c * 2 + 1];
  }
  __shared__ double s1[256], s2[256];
  s1[tid] = a; s2[tid] = q;
  __syncthreads();
  for (int s = 128; s > 0; s >>= 1) {
    if (tid < s) { s1[tid] += s1[tid + s]; s2[tid] += s2[tid + s]; }
    __syncthreads();
  }
  if (tid == 0) {
    double n = (double)BB * (lev ? P1v : P0v);
    double mu = s1[0] / n;
    double var = s2[0] / n - mu * mu;
    float rsig = 1.0f / sqrtf((float)var + 1e-5f);
    float A = gamma[c] * rsig;
    float Bv = beta[c] - (float)mu * A;
    float* cf = lev ? cf1 : cf0;
    cf[2 * c] = A;
    cf[2 * c + 1] = Bv;
  }
}

// ---- fused finalize + sew-up gather: branchless via code table ----
__global__ __launch_bounds__(256) void final_fused(
    const float* __restrict__ xtr, const float* __restrict__ y10,
    const float* __restrict__ y11, const float* __restrict__ cf0,
    const float* __restrict__ cf1, const int* __restrict__ codes,
    float* __restrict__ out) {
  const int bc = blockIdx.y;
  const int k = blockIdx.x * 256 + threadIdx.x;
  const int c = bc & 63;
  const float A0 = cf0[2 * c], B0 = cf0[2 * c + 1];
  const float A1 = cf1[2 * c], B1 = cf1[2 * c + 1];
  const float* xr  = xtr + (long)bc * TT;
  const float* y0r = y10 + (long)bc * V0v;
  const float* y1r = y11 + (long)bc * V1v;

  int code = codes[k];
  int type = code & 3;
  int xi = (code >> 2) & 4095;
  int yi = code >> 14;
  float xv = xr[xi];
  const float* yrow = (type == 2) ? y1r : y0r;
  float yv = yrow[yi];
  float A = (type == 0) ? 0.f : ((type == 2) ? A1 : A0);
  float Bv = (type == 0) ? 0.f : ((type == 2) ? B1 : B0);
  float z = fmaf(A, yv, Bv);
  float e = (z > 0.f) ? z : (expf(z) - 1.f);
  out[(long)bc * OUTL + k] = xv + e;
}

extern "C" void kernel_launch(void* const* d_in, const int* in_sizes, int n_in,
                              void* d_out, int out_size, void* d_ws, size_t ws_size,
                              hipStream_t stream) {
  const float* x   = (const float*)d_in[0];
  const float* cv  = (const float*)d_in[1];
  const float* cg  = (const float*)d_in[2];
  const float* cb  = (const float*)d_in[3];
  const float* gam = (const float*)d_in[4];
  const float* bet = (const float*)d_in[5];
  float* out = (float*)d_out;

  char* ws = (char*)d_ws;
  size_t cur = 0;
  auto alloc = [&](size_t bytes) -> char* {
    char* p = ws + cur;
    cur = (cur + bytes + 255) & ~(size_t)255;
    return p;
  };
  double* part   = (double*)alloc(4096 * 2 * sizeof(double));
  double* stats  = (double*)alloc(4 * sizeof(double));
  float*  wt     = (float*)alloc(3 * 64 * 64 * sizeof(float));
  float*  bnp    = (float*)alloc((size_t)NTILE * 128 * sizeof(float));
  float*  cf0    = (float*)alloc(128 * sizeof(float));
  float*  cf1    = (float*)alloc(128 * sizeof(float));
  int*    codes  = (int*)alloc(OUTL * sizeof(int));
  float*  xtr    = (float*)alloc((size_t)BB * CC * TT * sizeof(float));
  float*  y10    = (float*)alloc((size_t)4096 * V0v * sizeof(float));
  float*  y11    = (float*)alloc((size_t)4096 * V1v * sizeof(float));

  transpose_stats<<<dim3(64, 64), 256, 0, stream>>>(x, xtr, part);
  prep<<<89, 256, 0, stream>>>(part, stats, cv, cg, wt, codes);

  conv_pool<<<dim3(64, NB0 + NB1), 256, 0, stream>>>(x, wt, cb, stats, y10, y11, bnp);

  bn_reduce<<<128, 256, 0, stream>>>(bnp, gam, bet, cf0, cf1);

  final_fused<<<dim3(24, 4096), 256, 0, stream>>>(xtr, y10, y11, cf0, cf1, codes, out);
}

// Round 4
// 418.717 us; speedup vs baseline: 2.6079x; 2.6079x over previous
//
#include <hip/hip_runtime.h>
#include <math.h>

#define BB 64
#define TT 4096
#define CC 64

constexpr int L0v = 2048, U0v = 3069, V0v = 1535, P0v = 2048;
constexpr int L1v = 1024, U1v = 1533, V1v = 767,  P1v = 1024;
constexpr int OUTL = 6144;
constexpr long NTOT = (long)BB * TT * CC;
#define VB 34         // pool outputs per tile
#define NB0 46        // ceil(V0v/VB)
#define NB1 23        // ceil(V1v/VB)
#define NTILE ((NB0 + NB1) * 64)
#define SROWS 50      // staged rows per stream
#define CBSTR 65      // E-buffer stride (odd -> conflict-free column reads)

// ---- transpose x[b][t][c] -> xtr[b][c][t], fused global sum/sumsq ----
__global__ __launch_bounds__(256) void transpose_stats(const float* __restrict__ x,
                                                       float* __restrict__ xtr,
                                                       double* __restrict__ part) {
  __shared__ float tile[64][65];
  __shared__ double sd1[256], sd2[256];
  const int tt = blockIdx.x;
  const int b = blockIdx.y;
  const int t0 = tt * 64;
  const long xbase = (long)b * TT * CC + (long)t0 * CC;
  const int tid = threadIdx.x;
  double a = 0, q = 0;
  {
    int c = tid & 63;
    for (int r = tid >> 6; r < 64; r += 4) {
      float v = x[xbase + r * 64 + c];
      tile[r][c] = v;
      a += v; q += (double)v * (double)v;
    }
  }
  sd1[tid] = a; sd2[tid] = q;
  __syncthreads();
  {
    int tl = tid & 63;
    for (int cc = tid >> 6; cc < 64; cc += 4)
      xtr[((long)(b * 64 + cc)) * TT + t0 + tl] = tile[tl][cc];
  }
  for (int s = 128; s > 0; s >>= 1) {
    if (tid < s) { sd1[tid] += sd1[tid + s]; sd2[tid] += sd2[tid + s]; }
    __syncthreads();
  }
  if (tid == 0) {
    part[(b * 64 + tt) * 2] = sd1[0];
    part[(b * 64 + tt) * 2 + 1] = sd2[0];
  }
}

// ---------------- closed-form index helpers ----------------
__device__ __host__ inline int pad_idx(int p, int brk, int dup, int sub) {
  if (p < brk) { int q = p / 3; int r = p - 3 * q; return 2 * q + (r == 2 ? 1 : 0); }
  if (p < brk + 2) return dup;
  return p - sub;
}

__device__ inline int fmap_code(int k) {
  if (k == 0) return 2048 + 0;
  if (k == 1) return 0;
  if (k < 5462) {
    int m = k - 2;
    int c = m / 12;
    int j = m - 12 * c;
    if (j <= 3)  return 2048 + (1 + 9 * c + j);
    if (j == 4)  return 1 + 3 * c;
    if (j <= 8)  return 2048 + (9 * c + j);
    if (j == 9)  return 2 + 3 * c;
    if (j == 10) return 2048 + (9 + 9 * c);
    return 3 + 3 * c;
  }
  return k - 4096;
}

// ---- merged prep: block 0 = stats_final, 1..64 = weight_norm, 65..88 = codes ----
__global__ __launch_bounds__(256) void prep(const double* __restrict__ part,
                                            double* __restrict__ stats,
                                            const float* __restrict__ v,
                                            const float* __restrict__ g,
                                            float* __restrict__ wt,
                                            int* __restrict__ codes) {
  const int blk = blockIdx.x;
  const int tid = threadIdx.x;
  if (blk == 0) {
    __shared__ double s1[256], s2[256];
    double a = 0, q = 0;
    for (int i = tid; i < 4096; i += 256) { a += part[2 * i]; q += part[2 * i + 1]; }
    s1[tid] = a; s2[tid] = q;
    __syncthreads();
    for (int s = 128; s > 0; s >>= 1) {
      if (tid < s) { s1[tid] += s1[tid + s]; s2[tid] += s2[tid + s]; }
      __syncthreads();
    }
    if (tid == 0) {
      double n = (double)NTOT;
      double mean = s1[0] / n;
      double var = (s2[0] - s1[0] * s1[0] / n) / (n - 1.0);
      stats[0] = mean; stats[1] = sqrt(var);
      stats[2] = 0.8 / mean;
      stats[3] = 0.8 / sqrt(var);
    }
  } else if (blk <= 64) {
    int o = blk - 1;
    __shared__ float red[256];
    __shared__ float scale;
    float vv = (tid < 192) ? v[o * 192 + tid] : 0.f;
    red[tid] = vv * vv;
    __syncthreads();
    for (int s = 128; s > 0; s >>= 1) {
      if (tid < s) red[tid] += red[tid + s];
      __syncthreads();
    }
    if (tid == 0) scale = g[o] / sqrtf(red[0]);
    __syncthreads();
    if (tid < 192) {
      int i = tid / 3, k = tid - 3 * i;
      wt[(k * 64 + i) * 64 + o] = scale * vv;
    }
  } else {
    int k = (blk - 65) * 256 + tid;
    if (k < OUTL) {
      int s = fmap_code(k);
      int type, xi, yi = 0;
      if (s < 2048) {
        if ((s & 1) == 0) { type = 0; xi = 2 * s; }
        else { int p = s >> 1; yi = pad_idx(p, 768, 512, 257); xi = 4 * p + 3; type = 2; }
      } else {
        int p = s - 2048;
        if ((p & 1) == 0) { type = 0; xi = p; }
        else { int q = p >> 1; yi = pad_idx(q, 1536, 1024, 513); xi = 2 * q + 1; type = 1; }
      }
      codes[k] = type | (xi << 2) | (yi << 14);
    }
  }
}

// ---- fused conv (stride2, dil3) + bias + maxpool(3,s2,p1) + elu + gauss + bn-partials ----
// E-restructure (verified correct in round 3): for u = 3a+r,
//   m(3a)   = ivm*E1[2a] + 0.2*E0[2a]
//   m(3a+1) = ivs*E1[2a] + 0.2*E0[2a]
//   m(3a+2) = E0[2a+1]
// with E_s[tau] = sum_k sum_c x_s[tau+k][c]*w[k][c][o] (stride-1 convs of the
// raw streams).  lane = o; weights are coalesced per-lane loads; x rows are
// uniform-address LDS broadcasts.  Round-3 lesson: the ping-pong/macro form
// was fully unrolled by the compiler -> VGPR pressure blowout -> scratch
// spill (WRITE_SIZE 2.5GB, VALUBusy 20%).  This version: one i4 loop with
// "#pragma unroll 1" (small body, bounded live ranges), no ping-pong, and
// launch_bounds(256,4) so the allocator has 128 VGPRs of headroom.
__global__ __launch_bounds__(256, 4) void conv_pool(
    const float* __restrict__ x, const float* __restrict__ wt,
    const float* __restrict__ cbias, const double* __restrict__ stats,
    float* __restrict__ y10, float* __restrict__ y11,
    float* __restrict__ part) {
  const int b = blockIdx.x;
  const int jb = blockIdx.y;
  const bool lev0 = jb < NB0;
  const int v0 = (lev0 ? jb : jb - NB0) * VB;
  const int L = lev0 ? L0v : L1v;
  const int U = lev0 ? U0v : U1v;
  const int V = lev0 ? V0v : V1v;
  const int mult = lev0 ? 2 : 4;
  const int off1 = lev0 ? 1 : 3;
  const int mid = lev0 ? 1024 : 512;
  float* __restrict__ y1 = lev0 ? y10 : y11;

  const int tid = threadIdx.x;
  const int lane = tid & 63;
  const int w = tid >> 6;

  const int a0 = (v0 == 0) ? -1 : (2 * v0 - 1) / 3;

  // S0: stream x[mult*t], S1: stream x[mult*t+off1]; 50 rows x 64 ch fp32 each.
  // Overlay: cbf[72][65] E-buffer + red[512] for bn reduce (20768 B < 25600 B).
  __shared__ __align__(16) float S[2 * SROWS * 64];
  float* S0 = S;
  float* S1 = S + SROWS * 64;
  float* cbf = S;
  float* red = S + 72 * CBSTR;

  const float ivm = (float)stats[2];
  const float ivs = (float)stats[3];
  const long xbase = (long)b * TT * CC;

  // ---- stage the two raw streams (clamped rows) ----
  for (int idx = tid; idx < SROWS * 16; idx += 256) {
    int d = idx >> 4, c4 = (idx & 15) * 4;
    int T = 2 * a0 + d;
    int Tc = min(max(T, 0), L - 1);
    float4 v0r = *(const float4*)&x[xbase + (long)(mult * Tc) * CC + c4];
    float4 v1r = *(const float4*)&x[xbase + (long)(mult * Tc + off1) * CC + c4];
    *(float4*)&S0[d * 64 + c4] = v0r;
    *(float4*)&S1[d * 64 + c4] = v1r;
  }
  __syncthreads();

  // ---- FMA phase: each wave owns 12 E0 rows (d=12w+dd) + 6 E1 rows (e=6w+ee) ----
  float accA[12], accB[6];
#pragma unroll
  for (int i = 0; i < 12; i++) accA[i] = 0.f;
#pragma unroll
  for (int i = 0; i < 6; i++) accB[i] = 0.f;

  const float* wl = wt + lane;
  const float* Sb0 = S0 + (12 * w) * 64;
  const float* Sb1 = S1 + (12 * w) * 64;

#pragma unroll 1
  for (int i4 = 0; i4 < 16; i4++) {
    float wr[12];
#pragma unroll
    for (int k = 0; k < 3; k++)
#pragma unroll
      for (int di = 0; di < 4; di++)
        wr[k * 4 + di] = wl[(k * 64 + i4 * 4 + di) * 64];

    const float* p0 = Sb0 + i4 * 4;
#pragma unroll
    for (int t = 0; t < 14; t++) {
      float4 xv = *(const float4*)(p0 + t * 64);
      if (t < 12) {
        accA[t] = fmaf(xv.x, wr[0], accA[t]);
        accA[t] = fmaf(xv.y, wr[1], accA[t]);
        accA[t] = fmaf(xv.z, wr[2], accA[t]);
        accA[t] = fmaf(xv.w, wr[3], accA[t]);
      }
      if (t >= 1 && t <= 12) {
        accA[t - 1] = fmaf(xv.x, wr[4], accA[t - 1]);
        accA[t - 1] = fmaf(xv.y, wr[5], accA[t - 1]);
        accA[t - 1] = fmaf(xv.z, wr[6], accA[t - 1]);
        accA[t - 1] = fmaf(xv.w, wr[7], accA[t - 1]);
      }
      if (t >= 2) {
        accA[t - 2] = fmaf(xv.x, wr[8],  accA[t - 2]);
        accA[t - 2] = fmaf(xv.y, wr[9],  accA[t - 2]);
        accA[t - 2] = fmaf(xv.z, wr[10], accA[t - 2]);
        accA[t - 2] = fmaf(xv.w, wr[11], accA[t - 2]);
      }
    }

    const float* p1 = Sb1 + i4 * 4;
#pragma unroll
    for (int t = 0; t < 13; t++) {
      float4 xv = *(const float4*)(p1 + t * 64);
      if ((t & 1) == 0) {
        if (t < 12) {
          accB[t / 2] = fmaf(xv.x, wr[0], accB[t / 2]);
          accB[t / 2] = fmaf(xv.y, wr[1], accB[t / 2]);
          accB[t / 2] = fmaf(xv.z, wr[2], accB[t / 2]);
          accB[t / 2] = fmaf(xv.w, wr[3], accB[t / 2]);
        }
        if (t >= 2) {
          accB[t / 2 - 1] = fmaf(xv.x, wr[8],  accB[t / 2 - 1]);
          accB[t / 2 - 1] = fmaf(xv.y, wr[9],  accB[t / 2 - 1]);
          accB[t / 2 - 1] = fmaf(xv.z, wr[10], accB[t / 2 - 1]);
          accB[t / 2 - 1] = fmaf(xv.w, wr[11], accB[t / 2 - 1]);
        }
      } else {
        accB[(t - 1) / 2] = fmaf(xv.x, wr[4], accB[(t - 1) / 2]);
        accB[(t - 1) / 2] = fmaf(xv.y, wr[5], accB[(t - 1) / 2]);
        accB[(t - 1) / 2] = fmaf(xv.z, wr[6], accB[(t - 1) / 2]);
        accB[(t - 1) / 2] = fmaf(xv.w, wr[7], accB[(t - 1) / 2]);
      }
    }
  }

  __syncthreads();   // streams dead; write E-buffer overlay
#pragma unroll
  for (int dd = 0; dd < 12; dd++)
    cbf[(12 * w + dd) * CBSTR + lane] = accA[dd];
#pragma unroll
  for (int ee = 0; ee < 6; ee++)
    cbf[(48 + 6 * w + ee) * CBSTR + lane] = accB[ee];
  __syncthreads();

  // ---- combine + pool + elu + gauss + bn partials ----
  const int o = tid >> 2;
  const float bias = cbias[o];
  float a1 = 0.f, a2 = 0.f;
  for (int vq = tid & 3; vq < VB; vq += 4) {
    int v = v0 + vq;
    if (v < V) {
      float m3 = -INFINITY;
#pragma unroll
      for (int p = 0; p < 3; p++) {
        int u = 2 * v - 1 + p;
        float mv = -INFINITY;
        if (u >= 0 && u < U) {
          int a = u / 3;
          int r = u - 3 * a;
          int ai = a - a0;
          if (r == 2) {
            mv = cbf[(2 * ai + 1) * CBSTR + o] + bias;
          } else {
            float e1 = cbf[(48 + ai) * CBSTR + o];
            float e0 = cbf[(2 * ai) * CBSTR + o];
            mv = fmaf(r ? ivs : ivm, e1, fmaf(0.2f, e0, bias));
          }
        }
        m3 = fmaxf(m3, mv);
      }
      float e = (m3 > 0.f) ? m3 : (expf(m3) - 1.f);
      float y = expf(-0.5f * e * e);
      y1[(long)(b * 64 + o) * V + v] = y;
      float wv = (v < mid) ? (float)(2 - (v & 1)) : ((v == mid) ? 2.f : 1.f);
      a1 += wv * y;
      a2 += wv * y * y;
    }
  }
  red[o * 4 + (tid & 3)] = a1;
  red[256 + o * 4 + (tid & 3)] = a2;
  __syncthreads();
  if (tid < 64) {
    float s1 = red[tid * 4] + red[tid * 4 + 1] + red[tid * 4 + 2] + red[tid * 4 + 3];
    float s2 = red[256 + tid * 4] + red[256 + tid * 4 + 1] + red[256 + tid * 4 + 2] + red[256 + tid * 4 + 3];
    long tile = (long)jb * 64 + b;
    part[tile * 128 + tid * 2] = s1;
    part[tile * 128 + tid * 2 + 1] = s2;
  }
}

// ---- bn reduce over per-tile partials -> affine coefficients z = A*y + B ----
__global__ __launch_bounds__(256) void bn_reduce(const float* __restrict__ part,
                                                 const float* __restrict__ gamma,
                                                 const float* __restrict__ beta,
                                                 float* __restrict__ cf0,
                                                 float* __restrict__ cf1) {
  const int bc = blockIdx.x;          // 0..127
  const int lev = bc >> 6, c = bc & 63;
  const long t_lo = lev ? (long)NB0 * 64 : 0;
  const long t_hi = lev ? (long)(NB0 + NB1) * 64 : (long)NB0 * 64;
  const int tid = threadIdx.x;
  double a = 0, q = 0;
  for (long t = t_lo + tid; t < t_hi; t += 256) {
    a += part[t * 128 + c * 2];
    q += part[t * 128 + c * 2 + 1];
  }
  __shared__ double s1[256], s2[256];
  s1[tid] = a; s2[tid] = q;
  __syncthreads();
  for (int s = 128; s > 0; s >>= 1) {
    if (tid < s) { s1[tid] += s1[tid + s]; s2[tid] += s2[tid + s]; }
    __syncthreads();
  }
  if (tid == 0) {
    double n = (double)BB * (lev ? P1v : P0v);
    double mu = s1[0] / n;
    double var = s2[0] / n - mu * mu;
    float rsig = 1.0f / sqrtf((float)var + 1e-5f);
    float A = gamma[c] * rsig;
    float Bv = beta[c] - (float)mu * A;
    float* cf = lev ? cf1 : cf0;
    cf[2 * c] = A;
    cf[2 * c + 1] = Bv;
  }
}

// ---- fused finalize + sew-up gather: branchless via code table ----
__global__ __launch_bounds__(256) void final_fused(
    const float* __restrict__ xtr, const float* __restrict__ y10,
    const float* __restrict__ y11, const float* __restrict__ cf0,
    const float* __restrict__ cf1, const int* __restrict__ codes,
    float* __restrict__ out) {
  const int bc = blockIdx.y;
  const int k = blockIdx.x * 256 + threadIdx.x;
  const int c = bc & 63;
  const float A0 = cf0[2 * c], B0 = cf0[2 * c + 1];
  const float A1 = cf1[2 * c], B1 = cf1[2 * c + 1];
  const float* xr  = xtr + (long)bc * TT;
  const float* y0r = y10 + (long)bc * V0v;
  const float* y1r = y11 + (long)bc * V1v;

  int code = codes[k];
  int type = code & 3;
  int xi = (code >> 2) & 4095;
  int yi = code >> 14;
  float xv = xr[xi];
  const float* yrow = (type == 2) ? y1r : y0r;
  float yv = yrow[yi];
  float A = (type == 0) ? 0.f : ((type == 2) ? A1 : A0);
  float Bv = (type == 0) ? 0.f : ((type == 2) ? B1 : B0);
  float z = fmaf(A, yv, Bv);
  float e = (z > 0.f) ? z : (expf(z) - 1.f);
  out[(long)bc * OUTL + k] = xv + e;
}

extern "C" void kernel_launch(void* const* d_in, const int* in_sizes, int n_in,
                              void* d_out, int out_size, void* d_ws, size_t ws_size,
                              hipStream_t stream) {
  const float* x   = (const float*)d_in[0];
  const float* cv  = (const float*)d_in[1];
  const float* cg  = (const float*)d_in[2];
  const float* cb  = (const float*)d_in[3];
  const float* gam = (const float*)d_in[4];
  const float* bet = (const float*)d_in[5];
  float* out = (float*)d_out;

  char* ws = (char*)d_ws;
  size_t cur = 0;
  auto alloc = [&](size_t bytes) -> char* {
    char* p = ws + cur;
    cur = (cur + bytes + 255) & ~(size_t)255;
    return p;
  };
  double* part   = (double*)alloc(4096 * 2 * sizeof(double));
  double* stats  = (double*)alloc(4 * sizeof(double));
  float*  wt     = (float*)alloc(3 * 64 * 64 * sizeof(float));
  float*  bnp    = (float*)alloc((size_t)NTILE * 128 * sizeof(float));
  float*  cf0    = (float*)alloc(128 * sizeof(float));
  float*  cf1    = (float*)alloc(128 * sizeof(float));
  int*    codes  = (int*)alloc(OUTL * sizeof(int));
  float*  xtr    = (float*)alloc((size_t)BB * CC * TT * sizeof(float));
  float*  y10    = (float*)alloc((size_t)4096 * V0v * sizeof(float));
  float*  y11    = (float*)alloc((size_t)4096 * V1v * sizeof(float));

  transpose_stats<<<dim3(64, 64), 256, 0, stream>>>(x, xtr, part);
  prep<<<89, 256, 0, stream>>>(part, stats, cv, cg, wt, codes);

  conv_pool<<<dim3(64, NB0 + NB1), 256, 0, stream>>>(x, wt, cb, stats, y10, y11, bnp);

  bn_reduce<<<128, 256, 0, stream>>>(bnp, gam, bet, cf0, cf1);

  final_fused<<<dim3(24, 4096), 256, 0, stream>>>(xtr, y10, y11, cf0, cf1, codes, out);
}

// Round 5
// 362.651 us; speedup vs baseline: 3.0111x; 1.1546x over previous
//
#include <hip/hip_runtime.h>
#include <math.h>

#define BB 64
#define TT 4096
#define CC 64

constexpr int L0v = 2048, U0v = 3069, V0v = 1535, P0v = 2048;
constexpr int L1v = 1024, U1v = 1533, V1v = 767,  P1v = 1024;
constexpr int OUTL = 6144;
constexpr long NTOT = (long)BB * TT * CC;
#define VB 30         // pool outputs per tile (-> 21 a's, 42 E0 + 21 E1 = 63 rows)
#define NB0 52        // ceil(V0v/VB)
#define NB1 26        // ceil(V1v/VB)
#define NTILE ((NB0 + NB1) * 64)
#define SRTOT 87      // staged raw rows: 44 (X0) + 43 (X1)
#define RSTR 65       // odd word stride: bank = (row + c) mod 32 -> conflict-free
#define EROWS 63

// ---- transpose x[b][t][c] -> xtr[b][c][t], fused global sum/sumsq ----
__global__ __launch_bounds__(256) void transpose_stats(const float* __restrict__ x,
                                                       float* __restrict__ xtr,
                                                       double* __restrict__ part) {
  __shared__ float tile[64][65];
  __shared__ double sd1[256], sd2[256];
  const int tt = blockIdx.x;
  const int b = blockIdx.y;
  const int t0 = tt * 64;
  const long xbase = (long)b * TT * CC + (long)t0 * CC;
  const int tid = threadIdx.x;
  double a = 0, q = 0;
  {
    int c = tid & 63;
    for (int r = tid >> 6; r < 64; r += 4) {
      float v = x[xbase + r * 64 + c];
      tile[r][c] = v;
      a += v; q += (double)v * (double)v;
    }
  }
  sd1[tid] = a; sd2[tid] = q;
  __syncthreads();
  {
    int tl = tid & 63;
    for (int cc = tid >> 6; cc < 64; cc += 4)
      xtr[((long)(b * 64 + cc)) * TT + t0 + tl] = tile[tl][cc];
  }
  for (int s = 128; s > 0; s >>= 1) {
    if (tid < s) { sd1[tid] += sd1[tid + s]; sd2[tid] += sd2[tid + s]; }
    __syncthreads();
  }
  if (tid == 0) {
    part[(b * 64 + tt) * 2] = sd1[0];
    part[(b * 64 + tt) * 2 + 1] = sd2[0];
  }
}

// ---------------- closed-form index helpers ----------------
__device__ __host__ inline int pad_idx(int p, int brk, int dup, int sub) {
  if (p < brk) { int q = p / 3; int r = p - 3 * q; return 2 * q + (r == 2 ? 1 : 0); }
  if (p < brk + 2) return dup;
  return p - sub;
}

__device__ inline int fmap_code(int k) {
  if (k == 0) return 2048 + 0;
  if (k == 1) return 0;
  if (k < 5462) {
    int m = k - 2;
    int c = m / 12;
    int j = m - 12 * c;
    if (j <= 3)  return 2048 + (1 + 9 * c + j);
    if (j == 4)  return 1 + 3 * c;
    if (j <= 8)  return 2048 + (9 * c + j);
    if (j == 9)  return 2 + 3 * c;
    if (j == 10) return 2048 + (9 + 9 * c);
    return 3 + 3 * c;
  }
  return k - 4096;
}

// ---- merged prep: block 0 = stats_final, 1..64 = weight_norm, 65..88 = codes ----
__global__ __launch_bounds__(256) void prep(const double* __restrict__ part,
                                            double* __restrict__ stats,
                                            const float* __restrict__ v,
                                            const float* __restrict__ g,
                                            float* __restrict__ wt,
                                            int* __restrict__ codes) {
  const int blk = blockIdx.x;
  const int tid = threadIdx.x;
  if (blk == 0) {
    __shared__ double s1[256], s2[256];
    double a = 0, q = 0;
    for (int i = tid; i < 4096; i += 256) { a += part[2 * i]; q += part[2 * i + 1]; }
    s1[tid] = a; s2[tid] = q;
    __syncthreads();
    for (int s = 128; s > 0; s >>= 1) {
      if (tid < s) { s1[tid] += s1[tid + s]; s2[tid] += s2[tid + s]; }
      __syncthreads();
    }
    if (tid == 0) {
      double n = (double)NTOT;
      double mean = s1[0] / n;
      double var = (s2[0] - s1[0] * s1[0] / n) / (n - 1.0);
      stats[0] = mean; stats[1] = sqrt(var);
      stats[2] = 0.8 / mean;
      stats[3] = 0.8 / sqrt(var);
    }
  } else if (blk <= 64) {
    int o = blk - 1;
    __shared__ float red[256];
    __shared__ float scale;
    float vv = (tid < 192) ? v[o * 192 + tid] : 0.f;
    red[tid] = vv * vv;
    __syncthreads();
    for (int s = 128; s > 0; s >>= 1) {
      if (tid < s) red[tid] += red[tid + s];
      __syncthreads();
    }
    if (tid == 0) scale = g[o] / sqrtf(red[0]);
    __syncthreads();
    if (tid < 192) {
      int i = tid / 3, k = tid - 3 * i;
      wt[(k * 64 + i) * 64 + o] = scale * vv;
    }
  } else {
    int k = (blk - 65) * 256 + tid;
    if (k < OUTL) {
      int s = fmap_code(k);
      int type, xi, yi = 0;
      if (s < 2048) {
        if ((s & 1) == 0) { type = 0; xi = 2 * s; }
        else { int p = s >> 1; yi = pad_idx(p, 768, 512, 257); xi = 4 * p + 3; type = 2; }
      } else {
        int p = s - 2048;
        if ((p & 1) == 0) { type = 0; xi = p; }
        else { int q = p >> 1; yi = pad_idx(q, 1536, 1024, 513); xi = 2 * q + 1; type = 1; }
      }
      codes[k] = type | (xi << 2) | (yi << 14);
    }
  }
}

// ---- fused conv (stride2, dil3) + bias + maxpool(3,s2,p1) + elu + gauss + bn-partials ----
// E-restructure (math verified r3/r4): u = 3a+r,
//   m(3a)   = ivm*E1[2a] + 0.2*E0[2a]
//   m(3a+1) = ivs*E1[2a] + 0.2*E0[2a]
//   m(3a+2) = E0[2a+1]
// E_s[tau] = sum_k sum_c x_s[tau+k][c] * w[k][c][o].
// Round-4 lesson: lane=o (per-lane VGPR weights) is the slow shape (3-VGPR
// FMA operands + VMEM weight stream; 197us @91% busy).  This version uses
// round-2's proven fast shape: wave = 16-o group -> weights wave-uniform
// (s_load, scalar pipe, 2-VGPR-operand FMA), lane = E-row.  Lanes 0..41 do
// E0 rows, 42..62 do E1 rows -- identical instruction stream (shared
// weights), only the per-lane LDS base differs.  Stride-65 LDS rows: bank =
// (row+c) mod 32 -> conflict-free.  22.6 KB LDS -> 7 blocks/CU.
__global__ __launch_bounds__(256, 7) void conv_pool(
    const float* __restrict__ x, const float* __restrict__ wt,
    const float* __restrict__ cbias, const double* __restrict__ stats,
    float* __restrict__ y10, float* __restrict__ y11,
    float* __restrict__ part) {
  const int b = blockIdx.x;
  const int jb = blockIdx.y;
  const bool lev0 = jb < NB0;
  const int v0 = (lev0 ? jb : jb - NB0) * VB;
  const int L = lev0 ? L0v : L1v;
  const int U = lev0 ? U0v : U1v;
  const int V = lev0 ? V0v : V1v;
  const int mult = lev0 ? 2 : 4;
  const int off1 = lev0 ? 1 : 3;
  const int mid = lev0 ? 1024 : 512;
  float* __restrict__ y1 = lev0 ? y10 : y11;

  const int tid = threadIdx.x;
  const int lane = tid & 63;
  const int og = __builtin_amdgcn_readfirstlane((tid >> 6) * 16);

  const int a0 = (v0 == 0) ? 0 : (2 * v0 - 1) / 3;

  // rows 0..43: X0 tau = 2a0+d ; rows 44..86: X1 tau = 2a0+(d-44)
  // overlay: cbf[63][65] (4095 w) + red[512] at 4096 -> 4608 <= 87*65=5655
  __shared__ __align__(16) float S[SRTOT * RSTR];
  float* cbf = S;
  float* red = S + 4096;

  const float ivm = (float)stats[2];
  const float ivs = (float)stats[3];
  const long xbase = (long)b * TT * CC;

  // ---- stage both raw streams (clamped rows), [row][c] stride 65 ----
  for (int idx = tid; idx < SRTOT * 16; idx += 256) {
    int d = idx >> 4, c4 = (idx & 15) * 4;
    int T = (d < 44) ? (2 * a0 + d) : (2 * a0 + d - 44);
    int Tc = min(max(T, 0), L - 1);
    long row = (long)(mult * Tc) * CC + ((d < 44) ? 0 : off1) * CC;
    float4 vr = *(const float4*)&x[xbase + row + c4];
    float* dst = S + d * RSTR + c4;
    dst[0] = vr.x; dst[1] = vr.y; dst[2] = vr.z; dst[3] = vr.w;
  }
  __syncthreads();

  // ---- per-lane E-row base ----
  // lane 0..41  -> rho = lane        (E0[2a0+lane])
  // lane 42..62 -> rho = 44+2*(l-42) (E1[2a0+2*(l-42)])
  // lane 63     -> rho = 0 (dummy)
  const int rho = (lane <= 41) ? lane : ((lane == 63) ? 0 : (44 + 2 * (lane - 42)));
  const float* Sx = S + rho * RSTR;

  float acc[16];
#pragma unroll
  for (int oo = 0; oo < 16; oo++) acc[oo] = 0.f;

  for (int k = 0; k < 3; k++) {
    const float* Sk = Sx + k * RSTR;
    const float* wk = wt + (k * 64) * 64 + og;
#pragma unroll 4
    for (int i4 = 0; i4 < 16; i4++) {
      float x0 = Sk[i4 * 4 + 0];
      float x1 = Sk[i4 * 4 + 1];
      float x2 = Sk[i4 * 4 + 2];
      float x3 = Sk[i4 * 4 + 3];
      const float* wp = wk + i4 * 256;
#pragma unroll
      for (int oo = 0; oo < 16; oo++) {
        float w0 = wp[oo], w1 = wp[64 + oo], w2 = wp[128 + oo], w3 = wp[192 + oo];
        acc[oo] = fmaf(x0, w0, acc[oo]);
        acc[oo] = fmaf(x1, w1, acc[oo]);
        acc[oo] = fmaf(x2, w2, acc[oo]);
        acc[oo] = fmaf(x3, w3, acc[oo]);
      }
    }
  }

  __syncthreads();   // raw streams dead; reuse as E-buffer cbf[63][65]
  if (lane < EROWS) {
#pragma unroll
    for (int oo = 0; oo < 16; oo++)
      cbf[lane * RSTR + og + oo] = acc[oo];
  }
  __syncthreads();

  // ---- combine + pool + elu + gauss + bn partials ----
  // E-row index: E0[2a] -> 2*ai ; E0[2a+1] -> 2*ai+1 ; E1[2a] -> 42+ai
  const int o = tid >> 2;
  const float bias = cbias[o];
  float a1 = 0.f, a2 = 0.f;
  for (int vq = tid & 3; vq < VB; vq += 4) {
    int v = v0 + vq;
    if (v < V) {
      float m3 = -INFINITY;
#pragma unroll
      for (int p = 0; p < 3; p++) {
        int u = 2 * v - 1 + p;
        float mv = -INFINITY;
        if (u >= 0 && u < U) {
          int a = u / 3;
          int r = u - 3 * a;
          int ai = a - a0;
          if (r == 2) {
            mv = cbf[(2 * ai + 1) * RSTR + o] + bias;
          } else {
            float e1 = cbf[(42 + ai) * RSTR + o];
            float e0 = cbf[(2 * ai) * RSTR + o];
            mv = fmaf(r ? ivs : ivm, e1, fmaf(0.2f, e0, bias));
          }
        }
        m3 = fmaxf(m3, mv);
      }
      float e = (m3 > 0.f) ? m3 : (expf(m3) - 1.f);
      float y = expf(-0.5f * e * e);
      y1[(long)(b * 64 + o) * V + v] = y;
      float wv = (v < mid) ? (float)(2 - (v & 1)) : ((v == mid) ? 2.f : 1.f);
      a1 += wv * y;
      a2 += wv * y * y;
    }
  }
  red[o * 4 + (tid & 3)] = a1;
  red[256 + o * 4 + (tid & 3)] = a2;
  __syncthreads();
  if (tid < 64) {
    float s1 = red[tid * 4] + red[tid * 4 + 1] + red[tid * 4 + 2] + red[tid * 4 + 3];
    float s2 = red[256 + tid * 4] + red[256 + tid * 4 + 1] + red[256 + tid * 4 + 2] + red[256 + tid * 4 + 3];
    long tile = (long)jb * 64 + b;
    part[tile * 128 + tid * 2] = s1;
    part[tile * 128 + tid * 2 + 1] = s2;
  }
}

// ---- bn reduce over per-tile partials -> affine coefficients z = A*y + B ----
__global__ __launch_bounds__(256) void bn_reduce(const float* __restrict__ part,
                                                 const float* __restrict__ gamma,
                                                 const float* __restrict__ beta,
                                                 float* __restrict__ cf0,
                                                 float* __restrict__ cf1) {
  const int bc = blockIdx.x;          // 0..127
  const int lev = bc >> 6, c = bc & 63;
  const long t_lo = lev ? (long)NB0 * 64 : 0;
  const long t_hi = lev ? (long)(NB0 + NB1) * 64 : (long)NB0 * 64;
  const int tid = threadIdx.x;
  double a = 0, q = 0;
  for (long t = t_lo + tid; t < t_hi; t += 256) {
    a += part[t * 128 + c * 2];
    q += part[t * 128 + c * 2 + 1];
  }
  __shared__ double s1[256], s2[256];
  s1[tid] = a; s2[tid] = q;
  __syncthreads();
  for (int s = 128; s > 0; s >>= 1) {
    if (tid < s) { s1[tid] += s1[tid + s]; s2[tid] += s2[tid + s]; }
    __syncthreads();
  }
  if (tid == 0) {
    double n = (double)BB * (lev ? P1v : P0v);
    double mu = s1[0] / n;
    double var = s2[0] / n - mu * mu;
    float rsig = 1.0f / sqrtf((float)var + 1e-5f);
    float A = gamma[c] * rsig;
    float Bv = beta[c] - (float)mu * A;
    float* cf = lev ? cf1 : cf0;
    cf[2 * c] = A;
    cf[2 * c + 1] = Bv;
  }
}

// ---- fused finalize + sew-up gather: branchless via code table ----
__global__ __launch_bounds__(256) void final_fused(
    const float* __restrict__ xtr, const float* __restrict__ y10,
    const float* __restrict__ y11, const float* __restrict__ cf0,
    const float* __restrict__ cf1, const int* __restrict__ codes,
    float* __restrict__ out) {
  const int bc = blockIdx.y;
  const int k = blockIdx.x * 256 + threadIdx.x;
  const int c = bc & 63;
  const float A0 = cf0[2 * c], B0 = cf0[2 * c + 1];
  const float A1 = cf1[2 * c], B1 = cf1[2 * c + 1];
  const float* xr  = xtr + (long)bc * TT;
  const float* y0r = y10 + (long)bc * V0v;
  const float* y1r = y11 + (long)bc * V1v;

  int code = codes[k];
  int type = code & 3;
  int xi = (code >> 2) & 4095;
  int yi = code >> 14;
  float xv = xr[xi];
  const float* yrow = (type == 2) ? y1r : y0r;
  float yv = yrow[yi];
  float A = (type == 0) ? 0.f : ((type == 2) ? A1 : A0);
  float Bv = (type == 0) ? 0.f : ((type == 2) ? B1 : B0);
  float z = fmaf(A, yv, Bv);
  float e = (z > 0.f) ? z : (expf(z) - 1.f);
  out[(long)bc * OUTL + k] = xv + e;
}

extern "C" void kernel_launch(void* const* d_in, const int* in_sizes, int n_in,
                              void* d_out, int out_size, void* d_ws, size_t ws_size,
                              hipStream_t stream) {
  const float* x   = (const float*)d_in[0];
  const float* cv  = (const float*)d_in[1];
  const float* cg  = (const float*)d_in[2];
  const float* cb  = (const float*)d_in[3];
  const float* gam = (const float*)d_in[4];
  const float* bet = (const float*)d_in[5];
  float* out = (float*)d_out;

  char* ws = (char*)d_ws;
  size_t cur = 0;
  auto alloc = [&](size_t bytes) -> char* {
    char* p = ws + cur;
    cur = (cur + bytes + 255) & ~(size_t)255;
    return p;
  };
  double* part   = (double*)alloc(4096 * 2 * sizeof(double));
  double* stats  = (double*)alloc(4 * sizeof(double));
  float*  wt     = (float*)alloc(3 * 64 * 64 * sizeof(float));
  float*  bnp    = (float*)alloc((size_t)NTILE * 128 * sizeof(float));
  float*  cf0    = (float*)alloc(128 * sizeof(float));
  float*  cf1    = (float*)alloc(128 * sizeof(float));
  int*    codes  = (int*)alloc(OUTL * sizeof(int));
  float*  xtr    = (float*)alloc((size_t)BB * CC * TT * sizeof(float));
  float*  y10    = (float*)alloc((size_t)4096 * V0v * sizeof(float));
  float*  y11    = (float*)alloc((size_t)4096 * V1v * sizeof(float));

  transpose_stats<<<dim3(64, 64), 256, 0, stream>>>(x, xtr, part);
  prep<<<89, 256, 0, stream>>>(part, stats, cv, cg, wt, codes);

  conv_pool<<<dim3(64, NB0 + NB1), 256, 0, stream>>>(x, wt, cb, stats, y10, y11, bnp);

  bn_reduce<<<128, 256, 0, stream>>>(bnp, gam, bet, cf0, cf1);

  final_fused<<<dim3(24, 4096), 256, 0, stream>>>(xtr, y10, y11, cf0, cf1, codes, out);
}

// Round 6
// 316.940 us; speedup vs baseline: 3.4454x; 1.1442x over previous
//
#include <hip/hip_runtime.h>
#include <math.h>

#define BB 64
#define TT 4096
#define CC 64

constexpr int L0v = 2048, U0v = 3069, V0v = 1535, P0v = 2048;
constexpr int L1v = 1024, U1v = 1533, V1v = 767,  P1v = 1024;
constexpr int OUTL = 6144;
constexpr long NTOT = (long)BB * TT * CC;
#define VB 30         // pool outputs per tile (-> 21 a's, 42 E0 + 21 E1 = 63 rows)
#define NB0 52        // ceil(V0v/VB)
#define NB1 26        // ceil(V1v/VB)
#define NTILE ((NB0 + NB1) * 64)
#define SRTOT 87      // staged rows: 44 (X0) + 43 (X1)
#define GSTR 89       // float4-row stride for S2[16][GSTR] (odd -> staggered banks)
#define RSTR 65       // E-buffer stride (words)
#define EROWS 63

// ---- transpose x[b][t][c] -> xtr[b][c][t], fused global sum/sumsq ----
// float4 on both global sides; LDS tile stride 65 keeps both phases ~2-way.
__global__ __launch_bounds__(256) void transpose_stats(const float* __restrict__ x,
                                                       float* __restrict__ xtr,
                                                       double* __restrict__ part) {
  __shared__ float tile[64][65];
  __shared__ double sred[8];
  const int tt = blockIdx.x;
  const int b = blockIdx.y;
  const int t0 = tt * 64;
  const long xbase = (long)b * TT * CC + (long)t0 * CC;
  const int tid = threadIdx.x;
  double a = 0, q = 0;
  {
    const int c4 = (tid & 15) * 4;
    const int r0 = tid >> 4;
#pragma unroll
    for (int rr = 0; rr < 4; rr++) {
      int r = r0 + rr * 16;
      float4 v = *(const float4*)&x[xbase + r * 64 + c4];
      tile[r][c4] = v.x; tile[r][c4 + 1] = v.y;
      tile[r][c4 + 2] = v.z; tile[r][c4 + 3] = v.w;
      a += (double)v.x + (double)v.y + (double)v.z + (double)v.w;
      q += (double)v.x * v.x + (double)v.y * v.y + (double)v.z * v.z + (double)v.w * v.w;
    }
  }
  __syncthreads();
  {
    const int t4 = (tid & 15) * 4;
    const int c0 = tid >> 4;
#pragma unroll
    for (int cc = 0; cc < 4; cc++) {
      int c = c0 + cc * 16;
      float4 v;
      v.x = tile[t4][c]; v.y = tile[t4 + 1][c];
      v.z = tile[t4 + 2][c]; v.w = tile[t4 + 3][c];
      *(float4*)&xtr[((long)(b * 64 + c)) * TT + t0 + t4] = v;
    }
  }
  // wave shfl reduction, then tiny cross-wave combine
  for (int off = 32; off > 0; off >>= 1) {
    a += __shfl_down(a, off);
    q += __shfl_down(q, off);
  }
  if ((tid & 63) == 0) { sred[(tid >> 6) * 2] = a; sred[(tid >> 6) * 2 + 1] = q; }
  __syncthreads();
  if (tid == 0) {
    part[(b * 64 + tt) * 2]     = sred[0] + sred[2] + sred[4] + sred[6];
    part[(b * 64 + tt) * 2 + 1] = sred[1] + sred[3] + sred[5] + sred[7];
  }
}

// ---------------- closed-form index helpers ----------------
__device__ __host__ inline int pad_idx(int p, int brk, int dup, int sub) {
  if (p < brk) { int q = p / 3; int r = p - 3 * q; return 2 * q + (r == 2 ? 1 : 0); }
  if (p < brk + 2) return dup;
  return p - sub;
}

__device__ inline int fmap_code(int k) {
  if (k == 0) return 2048 + 0;
  if (k == 1) return 0;
  if (k < 5462) {
    int m = k - 2;
    int c = m / 12;
    int j = m - 12 * c;
    if (j <= 3)  return 2048 + (1 + 9 * c + j);
    if (j == 4)  return 1 + 3 * c;
    if (j <= 8)  return 2048 + (9 * c + j);
    if (j == 9)  return 2 + 3 * c;
    if (j == 10) return 2048 + (9 + 9 * c);
    return 3 + 3 * c;
  }
  return k - 4096;
}

// ---- merged prep: block 0 = stats_final, 1..64 = weight_norm, 65..88 = codes ----
__global__ __launch_bounds__(256) void prep(const double* __restrict__ part,
                                            double* __restrict__ stats,
                                            const float* __restrict__ v,
                                            const float* __restrict__ g,
                                            float* __restrict__ wt,
                                            int* __restrict__ codes) {
  const int blk = blockIdx.x;
  const int tid = threadIdx.x;
  if (blk == 0) {
    __shared__ double s1[256], s2[256];
    double a = 0, q = 0;
    for (int i = tid; i < 4096; i += 256) { a += part[2 * i]; q += part[2 * i + 1]; }
    s1[tid] = a; s2[tid] = q;
    __syncthreads();
    for (int s = 128; s > 0; s >>= 1) {
      if (tid < s) { s1[tid] += s1[tid + s]; s2[tid] += s2[tid + s]; }
      __syncthreads();
    }
    if (tid == 0) {
      double n = (double)NTOT;
      double mean = s1[0] / n;
      double var = (s2[0] - s1[0] * s1[0] / n) / (n - 1.0);
      stats[0] = mean; stats[1] = sqrt(var);
      stats[2] = 0.8 / mean;
      stats[3] = 0.8 / sqrt(var);
    }
  } else if (blk <= 64) {
    int o = blk - 1;
    __shared__ float red[256];
    __shared__ float scale;
    float vv = (tid < 192) ? v[o * 192 + tid] : 0.f;
    red[tid] = vv * vv;
    __syncthreads();
    for (int s = 128; s > 0; s >>= 1) {
      if (tid < s) red[tid] += red[tid + s];
      __syncthreads();
    }
    if (tid == 0) scale = g[o] / sqrtf(red[0]);
    __syncthreads();
    if (tid < 192) {
      int i = tid / 3, k = tid - 3 * i;
      wt[(k * 64 + i) * 64 + o] = scale * vv;
    }
  } else {
    int k = (blk - 65) * 256 + tid;
    if (k < OUTL) {
      int s = fmap_code(k);
      int type, xi, yi = 0;
      if (s < 2048) {
        if ((s & 1) == 0) { type = 0; xi = 2 * s; }
        else { int p = s >> 1; yi = pad_idx(p, 768, 512, 257); xi = 4 * p + 3; type = 2; }
      } else {
        int p = s - 2048;
        if ((p & 1) == 0) { type = 0; xi = p; }
        else { int q = p >> 1; yi = pad_idx(q, 1536, 1024, 513); xi = 2 * q + 1; type = 1; }
      }
      codes[k] = type | (xi << 2) | (yi << 14);
    }
  }
}

// ---- fused conv (stride2, dil3) + bias + maxpool(3,s2,p1) + elu + gauss + bn-partials ----
// E-restructure, wave-uniform weights (round-5 shape).  LDS layout is now
// channel-quad major: float4 S2[16][GSTR], element [g][tau] = x[tau][4g..4g+3].
// A lane's b128 read for (k,i4) sits at (i4*GSTR + rho+k)*16B: E0 lanes have
// consecutive rho -> contiguous 16B slices = the conflict-free streaming
// case (round-5's [row][c]-stride-65 b128 reads were ~4-way: 11.65M conflicts).
__global__ __launch_bounds__(256, 7) void conv_pool(
    const float* __restrict__ x, const float* __restrict__ wt,
    const float* __restrict__ cbias, const double* __restrict__ stats,
    float* __restrict__ y10, float* __restrict__ y11,
    float* __restrict__ part) {
  const int b = blockIdx.x;
  const int jb = blockIdx.y;
  const bool lev0 = jb < NB0;
  const int v0 = (lev0 ? jb : jb - NB0) * VB;
  const int L = lev0 ? L0v : L1v;
  const int U = lev0 ? U0v : U1v;
  const int V = lev0 ? V0v : V1v;
  const int mult = lev0 ? 2 : 4;
  const int off1 = lev0 ? 1 : 3;
  const int mid = lev0 ? 1024 : 512;
  float* __restrict__ y1 = lev0 ? y10 : y11;

  const int tid = threadIdx.x;
  const int lane = tid & 63;
  const int og = __builtin_amdgcn_readfirstlane((tid >> 6) * 16);

  const int a0 = (v0 == 0) ? 0 : (2 * v0 - 1) / 3;

  // S2: float4[16][89] = 22784 B.  Overlay: cbf[63][65] + red[512] (4608 fl <= 5696 fl)
  __shared__ __align__(16) float4 S2[16 * GSTR];
  float* cbf = (float*)S2;
  float* red = (float*)S2 + 4096;

  const float ivm = (float)stats[2];
  const float ivs = (float)stats[3];
  const long xbase = (long)b * TT * CC;

  // ---- stage both raw streams: S2[g][d] = x_row(d)[4g..4g+3] ----
  for (int idx = tid; idx < SRTOT * 16; idx += 256) {
    int d = idx >> 4, g = idx & 15;
    int T = (d < 44) ? (2 * a0 + d) : (2 * a0 + d - 44);
    int Tc = min(max(T, 0), L - 1);
    long row = (long)(mult * Tc) * CC + ((d < 44) ? 0 : off1) * CC;
    S2[g * GSTR + d] = *(const float4*)&x[xbase + row + g * 4];
  }
  __syncthreads();

  // lane 0..41 -> E0 row rho=lane ; 42..62 -> E1 row rho=44+2*(l-42) ; 63 dummy
  const int rho = (lane <= 41) ? lane : ((lane == 63) ? 0 : (44 + 2 * (lane - 42)));

  float acc[16];
#pragma unroll
  for (int oo = 0; oo < 16; oo++) acc[oo] = 0.f;

  for (int k = 0; k < 3; k++) {
    const float4* Sk = S2 + rho + k;
    const float* wk = wt + k * 4096 + og;
#pragma unroll 4
    for (int i4 = 0; i4 < 16; i4++) {
      float4 xv = Sk[i4 * GSTR];
      const float* wp = wk + i4 * 256;
#pragma unroll
      for (int oo = 0; oo < 16; oo++) {
        float w0 = wp[oo], w1 = wp[64 + oo], w2 = wp[128 + oo], w3 = wp[192 + oo];
        acc[oo] = fmaf(xv.x, w0, acc[oo]);
        acc[oo] = fmaf(xv.y, w1, acc[oo]);
        acc[oo] = fmaf(xv.z, w2, acc[oo]);
        acc[oo] = fmaf(xv.w, w3, acc[oo]);
      }
    }
  }

  __syncthreads();   // raw streams dead; reuse as E-buffer cbf[63][65]
  if (lane < EROWS) {
#pragma unroll
    for (int oo = 0; oo < 16; oo++)
      cbf[lane * RSTR + og + oo] = acc[oo];
  }
  __syncthreads();

  // ---- combine + pool + elu + gauss + bn partials ----
  // E-row index: E0[2a] -> 2*ai ; E0[2a+1] -> 2*ai+1 ; E1[2a] -> 42+ai
  const int o = tid >> 2;
  const float bias = cbias[o];
  float a1 = 0.f, a2 = 0.f;
  for (int vq = tid & 3; vq < VB; vq += 4) {
    int v = v0 + vq;
    if (v < V) {
      float m3 = -INFINITY;
#pragma unroll
      for (int p = 0; p < 3; p++) {
        int u = 2 * v - 1 + p;
        float mv = -INFINITY;
        if (u >= 0 && u < U) {
          int a = u / 3;
          int r = u - 3 * a;
          int ai = a - a0;
          if (r == 2) {
            mv = cbf[(2 * ai + 1) * RSTR + o] + bias;
          } else {
            float e1 = cbf[(42 + ai) * RSTR + o];
            float e0 = cbf[(2 * ai) * RSTR + o];
            mv = fmaf(r ? ivs : ivm, e1, fmaf(0.2f, e0, bias));
          }
        }
        m3 = fmaxf(m3, mv);
      }
      float e = (m3 > 0.f) ? m3 : (expf(m3) - 1.f);
      float y = expf(-0.5f * e * e);
      y1[(long)(b * 64 + o) * V + v] = y;
      float wv = (v < mid) ? (float)(2 - (v & 1)) : ((v == mid) ? 2.f : 1.f);
      a1 += wv * y;
      a2 += wv * y * y;
    }
  }
  red[o * 4 + (tid & 3)] = a1;
  red[256 + o * 4 + (tid & 3)] = a2;
  __syncthreads();
  if (tid < 64) {
    float s1 = red[tid * 4] + red[tid * 4 + 1] + red[tid * 4 + 2] + red[tid * 4 + 3];
    float s2 = red[256 + tid * 4] + red[256 + tid * 4 + 1] + red[256 + tid * 4 + 2] + red[256 + tid * 4 + 3];
    long tile = (long)jb * 64 + b;
    part[tile * 128 + tid * 2] = s1;
    part[tile * 128 + tid * 2 + 1] = s2;
  }
}

// ---- bn reduce over per-tile partials -> affine coefficients z = A*y + B ----
__global__ __launch_bounds__(256) void bn_reduce(const float* __restrict__ part,
                                                 const float* __restrict__ gamma,
                                                 const float* __restrict__ beta,
                                                 float* __restrict__ cf0,
                                                 float* __restrict__ cf1) {
  const int bc = blockIdx.x;          // 0..127
  const int lev = bc >> 6, c = bc & 63;
  const long t_lo = lev ? (long)NB0 * 64 : 0;
  const long t_hi = lev ? (long)(NB0 + NB1) * 64 : (long)NB0 * 64;
  const int tid = threadIdx.x;
  double a = 0, q = 0;
  for (long t = t_lo + tid; t < t_hi; t += 256) {
    a += part[t * 128 + c * 2];
    q += part[t * 128 + c * 2 + 1];
  }
  __shared__ double s1[256], s2[256];
  s1[tid] = a; s2[tid] = q;
  __syncthreads();
  for (int s = 128; s > 0; s >>= 1) {
    if (tid < s) { s1[tid] += s1[tid + s]; s2[tid] += s2[tid + s]; }
    __syncthreads();
  }
  if (tid == 0) {
    double n = (double)BB * (lev ? P1v : P0v);
    double mu = s1[0] / n;
    double var = s2[0] / n - mu * mu;
    float rsig = 1.0f / sqrtf((float)var + 1e-5f);
    float A = gamma[c] * rsig;
    float Bv = beta[c] - (float)mu * A;
    float* cf = lev ? cf1 : cf0;
    cf[2 * c] = A;
    cf[2 * c + 1] = Bv;
  }
}

// ---- fused finalize + sew-up gather, LDS-staged ----
// One block per (b,c) row.  Stage xtr row (16KB) + y0 (6KB) + y1 (3KB) with
// coalesced float4 loads; the 3 per-output gathers then hit LDS (native
// scatter) instead of splintering VMEM into ~40 cache lines per wave.
__global__ __launch_bounds__(256) void final_fused(
    const float* __restrict__ xtr, const float* __restrict__ y10,
    const float* __restrict__ y11, const float* __restrict__ cf0,
    const float* __restrict__ cf1, const int* __restrict__ codes,
    float* __restrict__ out) {
  const int bc = blockIdx.x;
  const int c = bc & 63;
  const int tid = threadIdx.x;
  __shared__ float xs[4096];
  __shared__ float y0s[1536];
  __shared__ float y1s[768];

  const float* xr = xtr + (long)bc * TT;
  for (int i = tid; i < 1024; i += 256)
    *(float4*)&xs[i * 4] = *(const float4*)&xr[i * 4];
  const float* y0r = y10 + (long)bc * V0v;
  for (int i = tid; i < 384; i += 256) {
    if (i < 383) *(float4*)&y0s[i * 4] = *(const float4*)&y0r[i * 4];
    else { y0s[1532] = y0r[1532]; y0s[1533] = y0r[1533]; y0s[1534] = y0r[1534]; }
  }
  const float* y1r = y11 + (long)bc * V1v;
  for (int i = tid; i < 192; i += 256) {
    if (i < 191) *(float4*)&y1s[i * 4] = *(const float4*)&y1r[i * 4];
    else { y1s[764] = y1r[764]; y1s[765] = y1r[765]; y1s[766] = y1r[766]; }
  }
  __syncthreads();

  const float A0 = cf0[2 * c], B0 = cf0[2 * c + 1];
  const float A1 = cf1[2 * c], B1 = cf1[2 * c + 1];
  float* orow = out + (long)bc * OUTL;
#pragma unroll 4
  for (int i = 0; i < 24; i++) {
    int k = i * 256 + tid;
    int code = codes[k];
    int type = code & 3;
    int xi = (code >> 2) & 4095;
    int yi = code >> 14;
    float xv = xs[xi];
    float yv = (type == 2) ? y1s[yi] : y0s[yi];
    float A = (type == 0) ? 0.f : ((type == 2) ? A1 : A0);
    float Bv = (type == 0) ? 0.f : ((type == 2) ? B1 : B0);
    float z = fmaf(A, yv, Bv);
    float e = (z > 0.f) ? z : (expf(z) - 1.f);
    orow[k] = xv + e;
  }
}

extern "C" void kernel_launch(void* const* d_in, const int* in_sizes, int n_in,
                              void* d_out, int out_size, void* d_ws, size_t ws_size,
                              hipStream_t stream) {
  const float* x   = (const float*)d_in[0];
  const float* cv  = (const float*)d_in[1];
  const float* cg  = (const float*)d_in[2];
  const float* cb  = (const float*)d_in[3];
  const float* gam = (const float*)d_in[4];
  const float* bet = (const float*)d_in[5];
  float* out = (float*)d_out;

  char* ws = (char*)d_ws;
  size_t cur = 0;
  auto alloc = [&](size_t bytes) -> char* {
    char* p = ws + cur;
    cur = (cur + bytes + 255) & ~(size_t)255;
    return p;
  };
  double* part   = (double*)alloc(4096 * 2 * sizeof(double));
  double* stats  = (double*)alloc(4 * sizeof(double));
  float*  wt     = (float*)alloc(3 * 64 * 64 * sizeof(float));
  float*  bnp    = (float*)alloc((size_t)NTILE * 128 * sizeof(float));
  float*  cf0    = (float*)alloc(128 * sizeof(float));
  float*  cf1    = (float*)alloc(128 * sizeof(float));
  int*    codes  = (int*)alloc(OUTL * sizeof(int));
  float*  xtr    = (float*)alloc((size_t)BB * CC * TT * sizeof(float));
  float*  y10    = (float*)alloc((size_t)4096 * V0v * sizeof(float));
  float*  y11    = (float*)alloc((size_t)4096 * V1v * sizeof(float));

  transpose_stats<<<dim3(64, 64), 256, 0, stream>>>(x, xtr, part);
  prep<<<89, 256, 0, stream>>>(part, stats, cv, cg, wt, codes);

  conv_pool<<<dim3(64, NB0 + NB1), 256, 0, stream>>>(x, wt, cb, stats, y10, y11, bnp);

  bn_reduce<<<128, 256, 0, stream>>>(bnp, gam, bet, cf0, cf1);

  final_fused<<<4096, 256, 0, stream>>>(xtr, y10, y11, cf0, cf1, codes, out);
}